// Round 8
// baseline (446.460 us; speedup 1.0000x reference)
//
#include <hip/hip_runtime.h>
#include <hip/hip_fp16.h>

#define NEG_SLOPE 0.2f
#define BKN 128                 // nodes per bucket (pow2)
#define MAXNB 1024              // supports n <= 131072
#define GRP 256                 // pass1/ghist groups (blocks), private cursors
#define LOG2E 1.44269504f

typedef _Float16 half_t;
typedef __attribute__((ext_vector_type(2))) _Float16 half2v;
typedef __attribute__((ext_vector_type(4))) _Float16 half4;
typedef __attribute__((ext_vector_type(8))) _Float16 half8;
typedef __attribute__((ext_vector_type(4))) float floatx4;

#if __has_builtin(__builtin_amdgcn_fdot2)
#define FDOT2(a, b, c) __builtin_amdgcn_fdot2((a), (b), (c), false)
#else
#define FDOT2(a, b, c) ((float)(a)[0] * (float)(b)[0] + (float)(a)[1] * (float)(b)[1] + (c))
#endif

// ---------------------------------------------------------------------------
// CSR build (2-level bucketed counting sort for scatter line-locality).
// NO per-node global atomics (round-6 evidence: they cost ~+35us).
// Weight convert for both layers folded in (first 96 blocks).
// ---------------------------------------------------------------------------
__global__ __launch_bounds__(256) void ghist_wconv(
    const int* __restrict__ ei, int E, int Etot, int NB, int chunk,
    int* __restrict__ cnt,
    const float* __restrict__ W1, half_t* __restrict__ Wt1,
    const float* __restrict__ W2, half_t* __restrict__ Wt2)
{
    int iw = blockIdx.x * 256 + threadIdx.x;
    if (iw < 128 * 128) {
        int k = iw / 128, nn = iw % 128;
        Wt1[nn * 128 + k] = (half_t)W1[iw];
    } else if (iw < 128 * 128 + 128 * 64) {
        int jx = iw - 128 * 128;
        int k = jx / 64, nn = jx % 64;
        Wt2[nn * 128 + k] = (half_t)W2[jx];
    }

    __shared__ int h[MAXNB];
    int g = blockIdx.x;
    for (int i = threadIdx.x; i < NB; i += 256) h[i] = 0;
    __syncthreads();
    int lo = g * chunk, hi = min(Etot, lo + chunk);
    for (int e = lo + threadIdx.x; e < hi; e += 256) {
        int dst = (e < E) ? ei[E + e] : (e - E);
        atomicAdd(&h[dst >> 7], 1);
    }
    __syncthreads();
    for (int i = threadIdx.x; i < NB; i += 256) cnt[i * GRP + g] = h[i];
}

// Per-1024 block scan (in-place exclusive); bsum = RAW block totals.
// Consumers prefix the <=256 totals themselves in LDS (scan_sums deleted).
__global__ __launch_bounds__(256) void scan_blocks(
    int* __restrict__ data, int n, int* __restrict__ bsum)
{
    __shared__ int s[256];
    int t = threadIdx.x;
    int idx = blockIdx.x * 1024 + t * 4;
    int4 v = make_int4(0, 0, 0, 0);
    if (idx + 3 < n)      v = *(const int4*)(data + idx);
    else {
        if (idx     < n) v.x = data[idx];
        if (idx + 1 < n) v.y = data[idx+1];
        if (idx + 2 < n) v.z = data[idx+2];
        if (idx + 3 < n) v.w = data[idx+3];
    }
    int tsum = v.x + v.y + v.z + v.w;
    s[t] = tsum;
    __syncthreads();
    for (int off = 1; off < 256; off <<= 1) {
        int x = (t >= off) ? s[t - off] : 0;
        __syncthreads();
        s[t] += x;
        __syncthreads();
    }
    int excl = s[t] - tsum;
    if (t == 255) bsum[blockIdx.x] = s[255];
    if (idx     < n) data[idx]     = excl;
    if (idx + 1 < n) data[idx + 1] = excl + v.x;
    if (idx + 2 < n) data[idx + 2] = excl + v.x + v.y;
    if (idx + 3 < n) data[idx + 3] = excl + v.x + v.y + v.z;
}

// ---------------------------------------------------------------------------
// FUSED: pass1_scatter (blocks [0,GRP)) + layer-1 MFMA GEMM (blocks >= GRP).
// pass1 branch prefixes the raw bsum totals in LDS (scratch overlays Wl so
// the kernel stays at 52KB -> 3 blocks/CU for the gemm path).
// ---------------------------------------------------------------------------
__global__ __launch_bounds__(256) void pass1_gemm1(
    const int* __restrict__ ei, int E, int Etot, int NB, int chunk, int nbC,
    const int* __restrict__ S, const int* __restrict__ bsum,
    unsigned* __restrict__ tmp,
    const float* __restrict__ X, const half_t* __restrict__ Wt,
    const float* __restrict__ atts, const float* __restrict__ attd,
    half_t* __restrict__ H, float* __restrict__ As, float* __restrict__ Ad,
    int n)
{
    constexpr int K = 128, BN = 128, NT = 8, HEADS = 4, TPH = 2;
    __shared__ half_t Wl[BN * K];          // 32KB (gemm path; pass1 scratch)
    __shared__ half_t Xl[64 * K];          // 16KB (gemm path)
    __shared__ int cur[MAXNB];             // 4KB  (pass1 path)

    const int t = threadIdx.x;

    if (blockIdx.x < GRP) {
        // ---------------- pass1_scatter ----------------
        int* bs  = (int*)Wl;               // [256] inclusive scan
        int* bse = (int*)Wl + 256;         // [256] exclusive prefix
        int g = blockIdx.x;
        int val = (t < nbC) ? bsum[t] : 0;
        bs[t] = val;
        __syncthreads();
        for (int off = 1; off < 256; off <<= 1) {
            int x = (t >= off) ? bs[t - off] : 0;
            __syncthreads();
            bs[t] += x;
            __syncthreads();
        }
        bse[t] = bs[t] - val;
        __syncthreads();
        for (int i = t; i < NB; i += 256) {
            int idx = i * GRP + g;
            cur[i] = S[idx] + bse[idx >> 10];
        }
        __syncthreads();
        int lo = g * chunk, hi = min(Etot, lo + chunk);
        for (int e = lo + t; e < hi; e += 256) {
            int src, dst;
            if (e < E) { src = ei[e]; dst = ei[E + e]; }
            else       { src = dst = e - E; }
            int pos = atomicAdd(&cur[dst >> 7], 1);   // LDS atomic, private row
            tmp[pos] = ((unsigned)src << 7) | (unsigned)(dst & (BKN - 1));
        }
        return;
    }

    // ---------------- layer-1 GEMM ----------------
    const int wave = t >> 6, lane = t & 63;
    const int quad = lane >> 4, c = lane & 15;

    float att_s[NT], att_d[NT];
    #pragma unroll
    for (int nt = 0; nt < NT; ++nt) {
        att_s[nt] = atts[nt * 16 + c] * LOG2E;
        att_d[nt] = attd[nt * 16 + c] * LOG2E;
    }

    for (int i = t; i < BN * 16; i += 256) {
        int row = i >> 4, cid = i & 15;
        half8 v = *(const half8*)(Wt + row * K + cid * 8);
        *(half8*)(Wl + row * K + ((cid ^ (row & 15)) << 3)) = v;
    }

    const int numTiles = (n + 63) / 64;
    for (int tile = blockIdx.x - GRP; tile < numTiles; tile += gridDim.x - GRP) {
        const int row0 = tile * 64;
        __syncthreads();
        for (int i = t; i < 1024; i += 256) {
            int m = i >> 4, cid = i & 15;
            int row = row0 + m;
            half8 h;
            #pragma unroll
            for (int z = 0; z < 8; ++z) h[z] = (half_t)0.f;
            if (row < n) {
                const float4* src = (const float4*)(X + (size_t)row * K + cid * 8);
                float4 a = src[0], b = src[1];
                h[0]=(half_t)a.x; h[1]=(half_t)a.y; h[2]=(half_t)a.z; h[3]=(half_t)a.w;
                h[4]=(half_t)b.x; h[5]=(half_t)b.y; h[6]=(half_t)b.z; h[7]=(half_t)b.w;
            }
            *(half8*)(Xl + m * K + ((cid ^ (m & 15)) << 3)) = h;
        }
        __syncthreads();

        floatx4 acc[NT];
        #pragma unroll
        for (int i = 0; i < NT; ++i) acc[i] = (floatx4)(0.f);

        #pragma unroll
        for (int kc = 0; kc < 4; ++kc) {
            int cid = kc * 4 + quad;
            half8 afrag = *(const half8*)(Xl + (wave * 16 + c) * K + ((cid ^ c) << 3));
            #pragma unroll
            for (int nt = 0; nt < NT; ++nt) {
                half8 bfrag = *(const half8*)(Wl + (nt * 16 + c) * K + ((cid ^ c) << 3));
                acc[nt] = __builtin_amdgcn_mfma_f32_16x16x32_f16(afrag, bfrag, acc[nt], 0, 0, 0);
            }
        }

        #pragma unroll
        for (int reg = 0; reg < 4; ++reg) {
            int row = row0 + wave * 16 + quad * 4 + reg;
            bool ok = row < n;
            if (ok) {
                #pragma unroll
                for (int nt = 0; nt < NT; ++nt)
                    H[(size_t)row * BN + nt * 16 + c] = (half_t)acc[nt][reg];
            }
            #pragma unroll
            for (int h = 0; h < HEADS; ++h) {
                float ps = 0.f, pd = 0.f;
                #pragma unroll
                for (int u = 0; u < TPH; ++u) {
                    int nt = h * TPH + u;
                    ps += acc[nt][reg] * att_s[nt];
                    pd += acc[nt][reg] * att_d[nt];
                }
                #pragma unroll
                for (int off = 1; off < 16; off <<= 1) {
                    ps += __shfl_xor(ps, off);
                    pd += __shfl_xor(pd, off);
                }
                if (ok && c == 0) {
                    As[(size_t)row * HEADS + h] = ps;
                    Ad[(size_t)row * HEADS + h] = pd;
                }
            }
        }
    }
}

// ---------------------------------------------------------------------------
// pass2_sort: count + scan + scatter (two streams over tmp; round-5 proven).
// Block-sum prefix folded in-LDS (scan_sums launch deleted).
// ---------------------------------------------------------------------------
__global__ __launch_bounds__(256) void pass2_sort(
    const unsigned* __restrict__ tmp, const int* __restrict__ S,
    const int* __restrict__ bsum, int NB, int Etot, int nbC,
    int* __restrict__ offs, int* __restrict__ esrc, int n)
{
    __shared__ int cnt[BKN];
    __shared__ int sc[BKN];
    __shared__ int cur[BKN];
    __shared__ int bs[256];
    __shared__ int bse[256];
    int bk = blockIdx.x;
    int t  = threadIdx.x;

    int val = (t < nbC) ? bsum[t] : 0;
    bs[t] = val;
    if (t < BKN) cnt[t] = 0;
    __syncthreads();
    for (int off = 1; off < 256; off <<= 1) {
        int x = (t >= off) ? bs[t - off] : 0;
        __syncthreads();
        bs[t] += x;
        __syncthreads();
    }
    bse[t] = bs[t] - val;
    __syncthreads();

    int lo = S[bk * GRP] + bse[(bk * GRP) >> 10];
    int hi = (bk + 1 < NB) ? (S[(bk + 1) * GRP] + bse[((bk + 1) * GRP) >> 10]) : Etot;

    for (int i = lo + t; i < hi; i += 256)
        atomicAdd(&cnt[tmp[i] & (BKN - 1)], 1);
    __syncthreads();
    int v = (t < BKN) ? cnt[t] : 0;
    if (t < BKN) sc[t] = v;
    __syncthreads();
    for (int off = 1; off < BKN; off <<= 1) {
        int x = (t < BKN && t >= off) ? sc[t - off] : 0;
        __syncthreads();
        if (t < BKN) sc[t] += x;
        __syncthreads();
    }
    if (t < BKN) {
        int node = bk * BKN + t;
        if (node < n) offs[node] = lo + sc[t];   // inclusive scan -> end(v)
        cur[t] = lo + sc[t] - v;                 // exclusive -> begin cursor
    }
    __syncthreads();
    for (int i = lo + t; i < hi; i += 256) {
        unsigned w = tmp[i];
        int p = atomicAdd(&cur[w & (BKN - 1)], 1);
        esrc[p] = (int)(w >> 7);
    }
}

// ---------------------------------------------------------------------------
// FUSED layer-1 aggregation + layer-2 GEMM row. One wave per dst node.
// Aggregation body identical to the proven agg1 (quarter-wave/edge, 4-edge
// unroll, dot2 MAC, exp2 logits). Epilogue: x2 row (fp16-rounded, identical
// numerics to the old X2h handoff) goes to LDS; all 64 lanes then compute one
// column of h2 = x2 @ W2 via dot2 against LDS-staged W2 (pair-packed), write
// H2 fp16 + cross-lane-reduced As2/Ad2 (pre-scaled by log2e). Deletes the
// standalone gemm2 launch and the entire 51.2MB X2 global round-trip.
// ---------------------------------------------------------------------------
__global__ __launch_bounds__(256) void agg1_fused(
    const int* __restrict__ offs, const int* __restrict__ esrc,
    const half8* __restrict__ H8, const float* __restrict__ As,
    const float* __restrict__ Ad, const float* __restrict__ bias,
    const half_t* __restrict__ Wt2,
    const float* __restrict__ atts2, const float* __restrict__ attd2,
    half_t* __restrict__ H2, float* __restrict__ As2, float* __restrict__ Ad2,
    int n)
{
    __shared__ half2v W2p[64 * 64];        // 16KB: W2p[k2][c] = (W2[2k2,c],W2[2k2+1,c])
    __shared__ half_t x2w[4 * 128];        // 1KB: per-wave x2 row staging

    const int t = threadIdx.x;
    for (int i = t; i < 64 * 64; i += 256)
        W2p[i] = *(const half2v*)(Wt2 + (i & 63) * 128 + ((i >> 6) << 1));
    __syncthreads();

    int v    = (blockIdx.x * 256 + t) >> 6;
    int lane = t & 63;
    if (v >= n) return;
    int wave = t >> 6;
    int q    = lane >> 4;        // quarter 0..3, one edge each
    int li   = lane & 15;        // feature lane: feats 8li..8li+7
    int head = li >> 2;          // 32 feats/head, 8 feats/lane -> 4 lanes/head
    int end = offs[v];
    int beg = v ? offs[v - 1] : 0;
    float adv = Ad[(size_t)v * 4 + head];
    float a2s = atts2[lane] * LOG2E;
    float a2d = attd2[lane] * LOG2E;
    half2v one; one[0] = (half_t)1.f; one[1] = (half_t)1.f;
    float a[8];
    #pragma unroll
    for (int f = 0; f < 8; ++f) a[f] = 0.f;
    float den = 0.f;
    int j = beg + q;
    for (; j + 12 < end; j += 16) {        // 4 edges per slot per iter
        int s0 = esrc[j], s1 = esrc[j + 4], s2 = esrc[j + 8], s3 = esrc[j + 12];
        float e0 = As[(unsigned)(s0 * 4 + head)] + adv;
        float e1 = As[(unsigned)(s1 * 4 + head)] + adv;
        float e2 = As[(unsigned)(s2 * 4 + head)] + adv;
        float e3 = As[(unsigned)(s3 * 4 + head)] + adv;
        half8 q0 = H8[(unsigned)(s0 * 16 + li)];
        half8 q1 = H8[(unsigned)(s1 * 16 + li)];
        half8 q2 = H8[(unsigned)(s2 * 16 + li)];
        half8 q3 = H8[(unsigned)(s3 * 16 + li)];
        float w0 = __builtin_amdgcn_exp2f(fmaxf(e0, NEG_SLOPE * e0));
        float w1 = __builtin_amdgcn_exp2f(fmaxf(e1, NEG_SLOPE * e1));
        float w2 = __builtin_amdgcn_exp2f(fmaxf(e2, NEG_SLOPE * e2));
        float w3 = __builtin_amdgcn_exp2f(fmaxf(e3, NEG_SLOPE * e3));
        half2v wp01; wp01[0] = (half_t)w0; wp01[1] = (half_t)w1;
        half2v wp23; wp23[0] = (half_t)w2; wp23[1] = (half_t)w3;
        #pragma unroll
        for (int f = 0; f < 8; ++f) {
            half2v p01; p01[0] = q0[f]; p01[1] = q1[f];
            half2v p23; p23[0] = q2[f]; p23[1] = q3[f];
            a[f] = FDOT2(p01, wp01, a[f]);
            a[f] = FDOT2(p23, wp23, a[f]);
        }
        den = FDOT2(wp01, one, den);
        den = FDOT2(wp23, one, den);
    }
    for (; j + 4 < end; j += 8) {          // 2-edge tail
        int s0 = esrc[j], s1 = esrc[j + 4];
        float e0 = As[(unsigned)(s0 * 4 + head)] + adv;
        float e1 = As[(unsigned)(s1 * 4 + head)] + adv;
        half8 q0 = H8[(unsigned)(s0 * 16 + li)];
        half8 q1 = H8[(unsigned)(s1 * 16 + li)];
        float w0 = __builtin_amdgcn_exp2f(fmaxf(e0, NEG_SLOPE * e0));
        float w1 = __builtin_amdgcn_exp2f(fmaxf(e1, NEG_SLOPE * e1));
        half2v wp; wp[0] = (half_t)w0; wp[1] = (half_t)w1;
        #pragma unroll
        for (int f = 0; f < 8; ++f) {
            half2v p; p[0] = q0[f]; p[1] = q1[f];
            a[f] = FDOT2(p, wp, a[f]);
        }
        den = FDOT2(wp, one, den);
    }
    for (; j < end; j += 4) {              // 1-edge tail
        int s = esrc[j];
        float e = As[(unsigned)(s * 4 + head)] + adv;
        half8 q0 = H8[(unsigned)(s * 16 + li)];
        float w = __builtin_amdgcn_exp2f(fmaxf(e, NEG_SLOPE * e));
        #pragma unroll
        for (int f = 0; f < 8; ++f) a[f] += w * (float)q0[f];
        den += w;
    }
    #pragma unroll
    for (int f = 0; f < 8; ++f) {
        a[f] += __shfl_xor(a[f], 16);
        a[f] += __shfl_xor(a[f], 32);
    }
    den += __shfl_xor(den, 16);
    den += __shfl_xor(den, 32);
    if (q == 0) {
        float inv = 1.f / (den + 1e-16f);
        float4 b0 = ((const float4*)bias)[2 * li];
        float4 b1 = ((const float4*)bias)[2 * li + 1];
        float o[8];
        o[0] = a[0] * inv + b0.x; o[1] = a[1] * inv + b0.y;
        o[2] = a[2] * inv + b0.z; o[3] = a[3] * inv + b0.w;
        o[4] = a[4] * inv + b1.x; o[5] = a[5] * inv + b1.y;
        o[6] = a[6] * inv + b1.z; o[7] = a[7] * inv + b1.w;
        half8 h;
        #pragma unroll
        for (int f = 0; f < 8; ++f) {
            float e = o[f] > 0.f ? o[f] : __expf(o[f]) - 1.f;
            h[f] = (half_t)e;
        }
        *(half8*)(x2w + wave * 128 + li * 8) = h;   // wave-internal LDS handoff
    }
    // ---- layer-2 GEMM row: lane c computes h2[v, c] = x2 . W2[:, c] ----
    const half8* xw8 = (const half8*)(x2w + wave * 128);
    float h2a = 0.f;
    #pragma unroll
    for (int k8 = 0; k8 < 16; ++k8) {
        half8 xq = xw8[k8];                // broadcast read (same addr, wave-order safe)
        #pragma unroll
        for (int jj = 0; jj < 4; ++jj) {
            half2v xp; xp[0] = xq[2 * jj]; xp[1] = xq[2 * jj + 1];
            h2a = FDOT2(xp, W2p[(k8 * 4 + jj) * 64 + lane], h2a);
        }
    }
    H2[(size_t)v * 64 + lane] = (half_t)h2a;
    float ps = h2a * a2s, pd = h2a * a2d;
    #pragma unroll
    for (int off = 1; off < 64; off <<= 1) {
        ps += __shfl_xor(ps, off);
        pd += __shfl_xor(pd, off);
    }
    if (lane == 0) { As2[v] = ps; Ad2[v] = pd; }
}

// ---------------------------------------------------------------------------
// Layer-2 aggregation: one wave per dst node; EIGHTH-WAVE per edge.
// 4-edge unroll per slot (32 edges/iter/wave); dot2 MAC; exp2 logits.
// ---------------------------------------------------------------------------
__global__ __launch_bounds__(256) void agg2(
    const int* __restrict__ offs, const int* __restrict__ esrc,
    const half8* __restrict__ H8, const float* __restrict__ As,
    const float* __restrict__ Ad, const float* __restrict__ bias,
    float* __restrict__ out, int n)
{
    int v    = (blockIdx.x * 256 + threadIdx.x) >> 6;
    int lane = threadIdx.x & 63;
    if (v >= n) return;
    int g  = lane >> 3;          // group 0..7, one edge each
    int li = lane & 7;           // feats 8li..8li+7
    int end = offs[v];
    int beg = v ? offs[v - 1] : 0;
    float adv = Ad[v];
    half2v one; one[0] = (half_t)1.f; one[1] = (half_t)1.f;
    float a[8];
    #pragma unroll
    for (int f = 0; f < 8; ++f) a[f] = 0.f;
    float den = 0.f;
    int j = beg + g;
    for (; j + 24 < end; j += 32) {        // 4 edges per slot per iter
        int s0 = esrc[j], s1 = esrc[j + 8], s2 = esrc[j + 16], s3 = esrc[j + 24];
        float e0 = As[s0] + adv;
        float e1 = As[s1] + adv;
        float e2 = As[s2] + adv;
        float e3 = As[s3] + adv;
        half8 q0 = H8[(unsigned)(s0 * 8 + li)];
        half8 q1 = H8[(unsigned)(s1 * 8 + li)];
        half8 q2 = H8[(unsigned)(s2 * 8 + li)];
        half8 q3 = H8[(unsigned)(s3 * 8 + li)];
        float w0 = __builtin_amdgcn_exp2f(fmaxf(e0, NEG_SLOPE * e0));
        float w1 = __builtin_amdgcn_exp2f(fmaxf(e1, NEG_SLOPE * e1));
        float w2 = __builtin_amdgcn_exp2f(fmaxf(e2, NEG_SLOPE * e2));
        float w3 = __builtin_amdgcn_exp2f(fmaxf(e3, NEG_SLOPE * e3));
        half2v wp01; wp01[0] = (half_t)w0; wp01[1] = (half_t)w1;
        half2v wp23; wp23[0] = (half_t)w2; wp23[1] = (half_t)w3;
        #pragma unroll
        for (int f = 0; f < 8; ++f) {
            half2v p01; p01[0] = q0[f]; p01[1] = q1[f];
            half2v p23; p23[0] = q2[f]; p23[1] = q3[f];
            a[f] = FDOT2(p01, wp01, a[f]);
            a[f] = FDOT2(p23, wp23, a[f]);
        }
        den = FDOT2(wp01, one, den);
        den = FDOT2(wp23, one, den);
    }
    for (; j + 8 < end; j += 16) {         // 2-edge tail
        int s0 = esrc[j], s1 = esrc[j + 8];
        float e0 = As[s0] + adv;
        float e1 = As[s1] + adv;
        half8 q0 = H8[(unsigned)(s0 * 8 + li)];
        half8 q1 = H8[(unsigned)(s1 * 8 + li)];
        float w0 = __builtin_amdgcn_exp2f(fmaxf(e0, NEG_SLOPE * e0));
        float w1 = __builtin_amdgcn_exp2f(fmaxf(e1, NEG_SLOPE * e1));
        half2v wp; wp[0] = (half_t)w0; wp[1] = (half_t)w1;
        #pragma unroll
        for (int f = 0; f < 8; ++f) {
            half2v p; p[0] = q0[f]; p[1] = q1[f];
            a[f] = FDOT2(p, wp, a[f]);
        }
        den = FDOT2(wp, one, den);
    }
    for (; j < end; j += 8) {              // 1-edge tail
        int s = esrc[j];
        float e = As[s] + adv;
        half8 q0 = H8[(unsigned)(s * 8 + li)];
        float w = __builtin_amdgcn_exp2f(fmaxf(e, NEG_SLOPE * e));
        #pragma unroll
        for (int f = 0; f < 8; ++f) a[f] += w * (float)q0[f];
        den += w;
    }
    #pragma unroll
    for (int f = 0; f < 8; ++f) {
        a[f] += __shfl_xor(a[f], 8);
        a[f] += __shfl_xor(a[f], 16);
        a[f] += __shfl_xor(a[f], 32);
    }
    den += __shfl_xor(den, 8);
    den += __shfl_xor(den, 16);
    den += __shfl_xor(den, 32);
    if (lane < 8) {
        float inv = 1.f / (den + 1e-16f);
        float4 b0 = ((const float4*)bias)[2 * li];
        float4 b1 = ((const float4*)bias)[2 * li + 1];
        float4* o4 = (float4*)(out + (size_t)v * 64);
        o4[2 * li]     = make_float4(a[0] * inv + b0.x, a[1] * inv + b0.y,
                                     a[2] * inv + b0.z, a[3] * inv + b0.w);
        o4[2 * li + 1] = make_float4(a[4] * inv + b1.x, a[5] * inv + b1.y,
                                     a[6] * inv + b1.z, a[7] * inv + b1.w);
    }
}

extern "C" void kernel_launch(void* const* d_in, const int* in_sizes, int n_in,
                              void* d_out, int out_size, void* d_ws, size_t ws_size,
                              hipStream_t stream)
{
    (void)n_in; (void)out_size; (void)ws_size;
    const float* x   = (const float*)d_in[0];
    const int*   ei  = (const int*)  d_in[1];
    const float* W1  = (const float*)d_in[2];
    const float* as1 = (const float*)d_in[3];
    const float* ad1 = (const float*)d_in[4];
    const float* b1  = (const float*)d_in[5];
    const float* W2  = (const float*)d_in[6];
    const float* as2 = (const float*)d_in[7];
    const float* ad2 = (const float*)d_in[8];
    const float* b2  = (const float*)d_in[9];
    float* out = (float*)d_out;

    const int n    = in_sizes[0] / 128;   // 100000
    const int E    = in_sizes[1] / 2;     // 1600000
    const int Etot = E + n;               // + self loops
    const int NB   = (n + BKN - 1) / BKN; // buckets (782)
    const int chunk = (Etot + GRP - 1) / GRP;

    // Workspace layout (bytes).
    char* p = (char*)d_ws;
    half_t* Hh  = (half_t*)p; p += (size_t)n * 128 * sizeof(half_t);  // 25.6MB
    half_t* H2  = (half_t*)p; p += (size_t)n * 64 * sizeof(half_t);   // 12.8MB
    float* As1 = (float*)p;   p += (size_t)n * 4 * sizeof(float);
    float* Ad1 = (float*)p;   p += (size_t)n * 4 * sizeof(float);
    float* As2 = (float*)p;   p += (size_t)n * sizeof(float);
    float* Ad2 = (float*)p;   p += (size_t)n * sizeof(float);
    int* offs  = (int*)p;     p += (size_t)n * sizeof(int);
    int* esrc  = (int*)p;     p += (size_t)Etot * sizeof(int);
    unsigned* tmp = (unsigned*)p; p += (size_t)Etot * sizeof(unsigned);
    int* cnt   = (int*)p;     p += (size_t)NB * GRP * sizeof(int);    // 0.8MB
    int* bsum  = (int*)p;     p += 1024;
    half_t* Wt1 = (half_t*)p; p += 128 * 128 * sizeof(half_t);        // 32KB
    half_t* Wt2 = (half_t*)p; p += 64 * 128 * sizeof(half_t);         // 16KB

    const int scan_n  = NB * GRP;
    const int scan_nb = (scan_n + 1023) / 1024;   // 196 <= 256

    const int gtiles = (n + 63) / 64;

    // ---- CSR build (wconv folded into ghist; gemm1 fused into pass1) ----
    ghist_wconv<<<GRP, 256, 0, stream>>>(ei, E, Etot, NB, chunk, cnt, W1, Wt1, W2, Wt2);
    scan_blocks<<<scan_nb, 256, 0, stream>>>(cnt, scan_n, bsum);
    pass1_gemm1<<<GRP + gtiles, 256, 0, stream>>>(ei, E, Etot, NB, chunk, scan_nb, cnt, bsum, tmp,
                                                  x, Wt1, as1, ad1, Hh, As1, Ad1, n);
    pass2_sort<<<NB, 256, 0, stream>>>(tmp, cnt, bsum, NB, Etot, scan_nb, offs, esrc, n);

    // ---- Layer 1 aggregation + layer-2 GEMM (fused; gemm2 launch deleted) ----
    agg1_fused<<<(n * 64 + 255) / 256, 256, 0, stream>>>(
        offs, esrc, (const half8*)Hh, As1, Ad1, b1,
        Wt2, as2, ad2, H2, As2, Ad2, n);

    // ---- Layer 2 aggregation ----
    agg2<<<(n * 64 + 255) / 256, 256, 0, stream>>>(offs, esrc, (const half8*)H2, As2, Ad2, b2, out, n);
}

// Round 9
// 302.090 us; speedup vs baseline: 1.4779x; 1.4779x over previous
//
#include <hip/hip_runtime.h>
#include <hip/hip_fp16.h>

#define NEG_SLOPE 0.2f
#define BKN 128                 // nodes per bucket (pow2)
#define MAXNB 1024              // supports n <= 131072
#define GRP 256                 // pass1/ghist groups (blocks), private cursors
#define LOG2E 1.44269504f

typedef _Float16 half_t;
typedef __attribute__((ext_vector_type(2))) _Float16 half2v;
typedef __attribute__((ext_vector_type(4))) _Float16 half4;
typedef __attribute__((ext_vector_type(8))) _Float16 half8;
typedef __attribute__((ext_vector_type(4))) float floatx4;

#if __has_builtin(__builtin_amdgcn_fdot2)
#define FDOT2(a, b, c) __builtin_amdgcn_fdot2((a), (b), (c), false)
#else
#define FDOT2(a, b, c) ((float)(a)[0] * (float)(b)[0] + (float)(a)[1] * (float)(b)[1] + (c))
#endif

// ---------------------------------------------------------------------------
// CSR build (2-level bucketed counting sort for scatter line-locality).
// NO per-node global atomics (round-6 evidence: they cost ~+35us).
// Weight convert for both layers folded in (first 96 blocks).
// ---------------------------------------------------------------------------
__global__ __launch_bounds__(256) void ghist_wconv(
    const int* __restrict__ ei, int E, int Etot, int NB, int chunk,
    int* __restrict__ cnt,
    const float* __restrict__ W1, half_t* __restrict__ Wt1,
    const float* __restrict__ W2, half_t* __restrict__ Wt2)
{
    int iw = blockIdx.x * 256 + threadIdx.x;
    if (iw < 128 * 128) {
        int k = iw / 128, nn = iw % 128;
        Wt1[nn * 128 + k] = (half_t)W1[iw];
    } else if (iw < 128 * 128 + 128 * 64) {
        int jx = iw - 128 * 128;
        int k = jx / 64, nn = jx % 64;
        Wt2[nn * 128 + k] = (half_t)W2[jx];
    }

    __shared__ int h[MAXNB];
    int g = blockIdx.x;
    for (int i = threadIdx.x; i < NB; i += 256) h[i] = 0;
    __syncthreads();
    int lo = g * chunk, hi = min(Etot, lo + chunk);
    for (int e = lo + threadIdx.x; e < hi; e += 256) {
        int dst = (e < E) ? ei[E + e] : (e - E);
        atomicAdd(&h[dst >> 7], 1);
    }
    __syncthreads();
    for (int i = threadIdx.x; i < NB; i += 256) cnt[i * GRP + g] = h[i];
}

// Per-1024 block scan (in-place exclusive); bsum = RAW block totals.
// Consumers prefix the <=256 totals themselves in LDS (scan_sums deleted).
__global__ __launch_bounds__(256) void scan_blocks(
    int* __restrict__ data, int n, int* __restrict__ bsum)
{
    __shared__ int s[256];
    int t = threadIdx.x;
    int idx = blockIdx.x * 1024 + t * 4;
    int4 v = make_int4(0, 0, 0, 0);
    if (idx + 3 < n)      v = *(const int4*)(data + idx);
    else {
        if (idx     < n) v.x = data[idx];
        if (idx + 1 < n) v.y = data[idx+1];
        if (idx + 2 < n) v.z = data[idx+2];
        if (idx + 3 < n) v.w = data[idx+3];
    }
    int tsum = v.x + v.y + v.z + v.w;
    s[t] = tsum;
    __syncthreads();
    for (int off = 1; off < 256; off <<= 1) {
        int x = (t >= off) ? s[t - off] : 0;
        __syncthreads();
        s[t] += x;
        __syncthreads();
    }
    int excl = s[t] - tsum;
    if (t == 255) bsum[blockIdx.x] = s[255];
    if (idx     < n) data[idx]     = excl;
    if (idx + 1 < n) data[idx + 1] = excl + v.x;
    if (idx + 2 < n) data[idx + 2] = excl + v.x + v.y;
    if (idx + 3 < n) data[idx + 3] = excl + v.x + v.y + v.z;
}

// ---------------------------------------------------------------------------
// FUSED: pass1_scatter (blocks [0,GRP)) + layer-1 MFMA GEMM (blocks >= GRP).
// pass1 branch prefixes the raw bsum totals in LDS (scratch overlays Wl so
// the kernel stays at 52KB -> 3 blocks/CU for the gemm path).
// ---------------------------------------------------------------------------
__global__ __launch_bounds__(256) void pass1_gemm1(
    const int* __restrict__ ei, int E, int Etot, int NB, int chunk, int nbC,
    const int* __restrict__ S, const int* __restrict__ bsum,
    unsigned* __restrict__ tmp,
    const float* __restrict__ X, const half_t* __restrict__ Wt,
    const float* __restrict__ atts, const float* __restrict__ attd,
    half_t* __restrict__ H, float* __restrict__ As, float* __restrict__ Ad,
    int n)
{
    constexpr int K = 128, BN = 128, NT = 8, HEADS = 4, TPH = 2;
    __shared__ half_t Wl[BN * K];          // 32KB (gemm path; pass1 scratch)
    __shared__ half_t Xl[64 * K];          // 16KB (gemm path)
    __shared__ int cur[MAXNB];             // 4KB  (pass1 path)

    const int t = threadIdx.x;

    if (blockIdx.x < GRP) {
        // ---------------- pass1_scatter ----------------
        int* bs  = (int*)Wl;               // [256] inclusive scan
        int* bse = (int*)Wl + 256;         // [256] exclusive prefix
        int g = blockIdx.x;
        int val = (t < nbC) ? bsum[t] : 0;
        bs[t] = val;
        __syncthreads();
        for (int off = 1; off < 256; off <<= 1) {
            int x = (t >= off) ? bs[t - off] : 0;
            __syncthreads();
            bs[t] += x;
            __syncthreads();
        }
        bse[t] = bs[t] - val;
        __syncthreads();
        for (int i = t; i < NB; i += 256) {
            int idx = i * GRP + g;
            cur[i] = S[idx] + bse[idx >> 10];
        }
        __syncthreads();
        int lo = g * chunk, hi = min(Etot, lo + chunk);
        for (int e = lo + t; e < hi; e += 256) {
            int src, dst;
            if (e < E) { src = ei[e]; dst = ei[E + e]; }
            else       { src = dst = e - E; }
            int pos = atomicAdd(&cur[dst >> 7], 1);   // LDS atomic, private row
            tmp[pos] = ((unsigned)src << 7) | (unsigned)(dst & (BKN - 1));
        }
        return;
    }

    // ---------------- layer-1 GEMM ----------------
    const int wave = t >> 6, lane = t & 63;
    const int quad = lane >> 4, c = lane & 15;

    float att_s[NT], att_d[NT];
    #pragma unroll
    for (int nt = 0; nt < NT; ++nt) {
        att_s[nt] = atts[nt * 16 + c] * LOG2E;
        att_d[nt] = attd[nt * 16 + c] * LOG2E;
    }

    for (int i = t; i < BN * 16; i += 256) {
        int row = i >> 4, cid = i & 15;
        half8 v = *(const half8*)(Wt + row * K + cid * 8);
        *(half8*)(Wl + row * K + ((cid ^ (row & 15)) << 3)) = v;
    }

    const int numTiles = (n + 63) / 64;
    for (int tile = blockIdx.x - GRP; tile < numTiles; tile += gridDim.x - GRP) {
        const int row0 = tile * 64;
        __syncthreads();
        for (int i = t; i < 1024; i += 256) {
            int m = i >> 4, cid = i & 15;
            int row = row0 + m;
            half8 h;
            #pragma unroll
            for (int z = 0; z < 8; ++z) h[z] = (half_t)0.f;
            if (row < n) {
                const float4* src = (const float4*)(X + (size_t)row * K + cid * 8);
                float4 a = src[0], b = src[1];
                h[0]=(half_t)a.x; h[1]=(half_t)a.y; h[2]=(half_t)a.z; h[3]=(half_t)a.w;
                h[4]=(half_t)b.x; h[5]=(half_t)b.y; h[6]=(half_t)b.z; h[7]=(half_t)b.w;
            }
            *(half8*)(Xl + m * K + ((cid ^ (m & 15)) << 3)) = h;
        }
        __syncthreads();

        floatx4 acc[NT];
        #pragma unroll
        for (int i = 0; i < NT; ++i) acc[i] = (floatx4)(0.f);

        #pragma unroll
        for (int kc = 0; kc < 4; ++kc) {
            int cid = kc * 4 + quad;
            half8 afrag = *(const half8*)(Xl + (wave * 16 + c) * K + ((cid ^ c) << 3));
            #pragma unroll
            for (int nt = 0; nt < NT; ++nt) {
                half8 bfrag = *(const half8*)(Wl + (nt * 16 + c) * K + ((cid ^ c) << 3));
                acc[nt] = __builtin_amdgcn_mfma_f32_16x16x32_f16(afrag, bfrag, acc[nt], 0, 0, 0);
            }
        }

        #pragma unroll
        for (int reg = 0; reg < 4; ++reg) {
            int row = row0 + wave * 16 + quad * 4 + reg;
            bool ok = row < n;
            if (ok) {
                #pragma unroll
                for (int nt = 0; nt < NT; ++nt)
                    H[(size_t)row * BN + nt * 16 + c] = (half_t)acc[nt][reg];
            }
            #pragma unroll
            for (int h = 0; h < HEADS; ++h) {
                float ps = 0.f, pd = 0.f;
                #pragma unroll
                for (int u = 0; u < TPH; ++u) {
                    int nt = h * TPH + u;
                    ps += acc[nt][reg] * att_s[nt];
                    pd += acc[nt][reg] * att_d[nt];
                }
                #pragma unroll
                for (int off = 1; off < 16; off <<= 1) {
                    ps += __shfl_xor(ps, off);
                    pd += __shfl_xor(pd, off);
                }
                if (ok && c == 0) {
                    As[(size_t)row * HEADS + h] = ps;
                    Ad[(size_t)row * HEADS + h] = pd;
                }
            }
        }
    }
}

// ---------------------------------------------------------------------------
// pass2_sort: count + scan + scatter (two streams over tmp; round-5 proven).
// Block-sum prefix folded in-LDS (scan_sums launch deleted).
// ---------------------------------------------------------------------------
__global__ __launch_bounds__(256) void pass2_sort(
    const unsigned* __restrict__ tmp, const int* __restrict__ S,
    const int* __restrict__ bsum, int NB, int Etot, int nbC,
    int* __restrict__ offs, int* __restrict__ esrc, int n)
{
    __shared__ int cnt[BKN];
    __shared__ int sc[BKN];
    __shared__ int cur[BKN];
    __shared__ int bs[256];
    __shared__ int bse[256];
    int bk = blockIdx.x;
    int t  = threadIdx.x;

    int val = (t < nbC) ? bsum[t] : 0;
    bs[t] = val;
    if (t < BKN) cnt[t] = 0;
    __syncthreads();
    for (int off = 1; off < 256; off <<= 1) {
        int x = (t >= off) ? bs[t - off] : 0;
        __syncthreads();
        bs[t] += x;
        __syncthreads();
    }
    bse[t] = bs[t] - val;
    __syncthreads();

    int lo = S[bk * GRP] + bse[(bk * GRP) >> 10];
    int hi = (bk + 1 < NB) ? (S[(bk + 1) * GRP] + bse[((bk + 1) * GRP) >> 10]) : Etot;

    for (int i = lo + t; i < hi; i += 256)
        atomicAdd(&cnt[tmp[i] & (BKN - 1)], 1);
    __syncthreads();
    int v = (t < BKN) ? cnt[t] : 0;
    if (t < BKN) sc[t] = v;
    __syncthreads();
    for (int off = 1; off < BKN; off <<= 1) {
        int x = (t < BKN && t >= off) ? sc[t - off] : 0;
        __syncthreads();
        if (t < BKN) sc[t] += x;
        __syncthreads();
    }
    if (t < BKN) {
        int node = bk * BKN + t;
        if (node < n) offs[node] = lo + sc[t];   // inclusive scan -> end(v)
        cur[t] = lo + sc[t] - v;                 // exclusive -> begin cursor
    }
    __syncthreads();
    for (int i = lo + t; i < hi; i += 256) {
        unsigned w = tmp[i];
        int p = atomicAdd(&cur[w & (BKN - 1)], 1);
        esrc[p] = (int)(w >> 7);
    }
}

// ---------------------------------------------------------------------------
// FUSED layer-1 aggregation + layer-2 GEMM row. One wave per dst node.
// Aggregation body identical to the proven agg1. Epilogue: x2 row (fp16-
// rounded) goes to wave-local LDS; all 64 lanes then compute one column of
// h2 = x2 @ W2. W2 is LDS-staged with the gemm's proven COALESCED half8 load
// + XOR-chunk swizzle (round-8's strided 4B staging was the 3.4x regression:
// 64 L1 line-transactions per wave instr). Lane c reads its swizzled row
// (conflict-free, same pattern the MFMA gemm runs); dot via 2 independent
// FDOT2 chains. Writes H2 fp16 + reduced As2/Ad2 (pre-scaled by log2e).
// Deletes the standalone gemm2 launch and the X2 global round-trip.
// ---------------------------------------------------------------------------
__global__ __launch_bounds__(256) void agg1_fused(
    const int* __restrict__ offs, const int* __restrict__ esrc,
    const half8* __restrict__ H8, const float* __restrict__ As,
    const float* __restrict__ Ad, const float* __restrict__ bias,
    const half_t* __restrict__ Wt2,
    const float* __restrict__ atts2, const float* __restrict__ attd2,
    half_t* __restrict__ H2, float* __restrict__ As2, float* __restrict__ Ad2,
    int n)
{
    __shared__ half_t W2l[64 * 128];       // 16KB, XOR-chunk swizzled rows
    __shared__ half_t x2w[4 * 128];        // 1KB: per-wave x2 row staging

    const int t = threadIdx.x;
    for (int i = t; i < 64 * 16; i += 256) {           // coalesced: wave reads 1KB contiguous
        int row = i >> 4, cid = i & 15;
        half8 vv = *(const half8*)(Wt2 + row * 128 + cid * 8);
        *(half8*)(W2l + row * 128 + ((cid ^ (row & 15)) << 3)) = vv;
    }
    __syncthreads();

    int v    = (blockIdx.x * 256 + t) >> 6;
    int lane = t & 63;
    if (v >= n) return;
    int wave = t >> 6;
    int q    = lane >> 4;        // quarter 0..3, one edge each
    int li   = lane & 15;        // feature lane: feats 8li..8li+7
    int head = li >> 2;          // 32 feats/head, 8 feats/lane -> 4 lanes/head
    int end = offs[v];
    int beg = v ? offs[v - 1] : 0;
    float adv = Ad[(size_t)v * 4 + head];
    float a2s = atts2[lane] * LOG2E;
    float a2d = attd2[lane] * LOG2E;
    half2v one; one[0] = (half_t)1.f; one[1] = (half_t)1.f;
    float a[8];
    #pragma unroll
    for (int f = 0; f < 8; ++f) a[f] = 0.f;
    float den = 0.f;
    int j = beg + q;
    for (; j + 12 < end; j += 16) {        // 4 edges per slot per iter
        int s0 = esrc[j], s1 = esrc[j + 4], s2 = esrc[j + 8], s3 = esrc[j + 12];
        float e0 = As[(unsigned)(s0 * 4 + head)] + adv;
        float e1 = As[(unsigned)(s1 * 4 + head)] + adv;
        float e2 = As[(unsigned)(s2 * 4 + head)] + adv;
        float e3 = As[(unsigned)(s3 * 4 + head)] + adv;
        half8 q0 = H8[(unsigned)(s0 * 16 + li)];
        half8 q1 = H8[(unsigned)(s1 * 16 + li)];
        half8 q2 = H8[(unsigned)(s2 * 16 + li)];
        half8 q3 = H8[(unsigned)(s3 * 16 + li)];
        float w0 = __builtin_amdgcn_exp2f(fmaxf(e0, NEG_SLOPE * e0));
        float w1 = __builtin_amdgcn_exp2f(fmaxf(e1, NEG_SLOPE * e1));
        float w2 = __builtin_amdgcn_exp2f(fmaxf(e2, NEG_SLOPE * e2));
        float w3 = __builtin_amdgcn_exp2f(fmaxf(e3, NEG_SLOPE * e3));
        half2v wp01; wp01[0] = (half_t)w0; wp01[1] = (half_t)w1;
        half2v wp23; wp23[0] = (half_t)w2; wp23[1] = (half_t)w3;
        #pragma unroll
        for (int f = 0; f < 8; ++f) {
            half2v p01; p01[0] = q0[f]; p01[1] = q1[f];
            half2v p23; p23[0] = q2[f]; p23[1] = q3[f];
            a[f] = FDOT2(p01, wp01, a[f]);
            a[f] = FDOT2(p23, wp23, a[f]);
        }
        den = FDOT2(wp01, one, den);
        den = FDOT2(wp23, one, den);
    }
    for (; j + 4 < end; j += 8) {          // 2-edge tail
        int s0 = esrc[j], s1 = esrc[j + 4];
        float e0 = As[(unsigned)(s0 * 4 + head)] + adv;
        float e1 = As[(unsigned)(s1 * 4 + head)] + adv;
        half8 q0 = H8[(unsigned)(s0 * 16 + li)];
        half8 q1 = H8[(unsigned)(s1 * 16 + li)];
        float w0 = __builtin_amdgcn_exp2f(fmaxf(e0, NEG_SLOPE * e0));
        float w1 = __builtin_amdgcn_exp2f(fmaxf(e1, NEG_SLOPE * e1));
        half2v wp; wp[0] = (half_t)w0; wp[1] = (half_t)w1;
        #pragma unroll
        for (int f = 0; f < 8; ++f) {
            half2v p; p[0] = q0[f]; p[1] = q1[f];
            a[f] = FDOT2(p, wp, a[f]);
        }
        den = FDOT2(wp, one, den);
    }
    for (; j < end; j += 4) {              // 1-edge tail
        int s = esrc[j];
        float e = As[(unsigned)(s * 4 + head)] + adv;
        half8 q0 = H8[(unsigned)(s * 16 + li)];
        float w = __builtin_amdgcn_exp2f(fmaxf(e, NEG_SLOPE * e));
        #pragma unroll
        for (int f = 0; f < 8; ++f) a[f] += w * (float)q0[f];
        den += w;
    }
    #pragma unroll
    for (int f = 0; f < 8; ++f) {
        a[f] += __shfl_xor(a[f], 16);
        a[f] += __shfl_xor(a[f], 32);
    }
    den += __shfl_xor(den, 16);
    den += __shfl_xor(den, 32);
    if (q == 0) {
        float inv = 1.f / (den + 1e-16f);
        float4 b0 = ((const float4*)bias)[2 * li];
        float4 b1 = ((const float4*)bias)[2 * li + 1];
        float o[8];
        o[0] = a[0] * inv + b0.x; o[1] = a[1] * inv + b0.y;
        o[2] = a[2] * inv + b0.z; o[3] = a[3] * inv + b0.w;
        o[4] = a[4] * inv + b1.x; o[5] = a[5] * inv + b1.y;
        o[6] = a[6] * inv + b1.z; o[7] = a[7] * inv + b1.w;
        half8 h;
        #pragma unroll
        for (int f = 0; f < 8; ++f) {
            float e = o[f] > 0.f ? o[f] : __expf(o[f]) - 1.f;
            h[f] = (half_t)e;
        }
        *(half8*)(x2w + wave * 128 + li * 8) = h;   // wave-internal LDS handoff
    }
    // ---- layer-2 GEMM row: lane c computes h2[v, c] = x2 . W2[:, c] ----
    const half8* xw8 = (const half8*)(x2w + wave * 128);
    float h2a = 0.f, h2b = 0.f;
    #pragma unroll
    for (int k8 = 0; k8 < 16; ++k8) {
        half8 xq = xw8[k8];                // broadcast read (same addr, wave-order safe)
        half8 wq = *(const half8*)(W2l + lane * 128 + ((k8 ^ (lane & 15)) << 3));
        #pragma unroll
        for (int jj = 0; jj < 4; ++jj) {
            half2v xp; xp[0] = xq[2 * jj]; xp[1] = xq[2 * jj + 1];
            half2v wp; wp[0] = wq[2 * jj]; wp[1] = wq[2 * jj + 1];
            if (jj & 1) h2b = FDOT2(xp, wp, h2b);
            else        h2a = FDOT2(xp, wp, h2a);
        }
    }
    float h2 = h2a + h2b;
    H2[(size_t)v * 64 + lane] = (half_t)h2;
    float ps = h2 * a2s, pd = h2 * a2d;
    #pragma unroll
    for (int off = 1; off < 64; off <<= 1) {
        ps += __shfl_xor(ps, off);
        pd += __shfl_xor(pd, off);
    }
    if (lane == 0) { As2[v] = ps; Ad2[v] = pd; }
}

// ---------------------------------------------------------------------------
// Layer-2 aggregation: one wave per dst node; EIGHTH-WAVE per edge.
// 4-edge unroll per slot (32 edges/iter/wave); dot2 MAC; exp2 logits.
// ---------------------------------------------------------------------------
__global__ __launch_bounds__(256) void agg2(
    const int* __restrict__ offs, const int* __restrict__ esrc,
    const half8* __restrict__ H8, const float* __restrict__ As,
    const float* __restrict__ Ad, const float* __restrict__ bias,
    float* __restrict__ out, int n)
{
    int v    = (blockIdx.x * 256 + threadIdx.x) >> 6;
    int lane = threadIdx.x & 63;
    if (v >= n) return;
    int g  = lane >> 3;          // group 0..7, one edge each
    int li = lane & 7;           // feats 8li..8li+7
    int end = offs[v];
    int beg = v ? offs[v - 1] : 0;
    float adv = Ad[v];
    half2v one; one[0] = (half_t)1.f; one[1] = (half_t)1.f;
    float a[8];
    #pragma unroll
    for (int f = 0; f < 8; ++f) a[f] = 0.f;
    float den = 0.f;
    int j = beg + g;
    for (; j + 24 < end; j += 32) {        // 4 edges per slot per iter
        int s0 = esrc[j], s1 = esrc[j + 8], s2 = esrc[j + 16], s3 = esrc[j + 24];
        float e0 = As[s0] + adv;
        float e1 = As[s1] + adv;
        float e2 = As[s2] + adv;
        float e3 = As[s3] + adv;
        half8 q0 = H8[(unsigned)(s0 * 8 + li)];
        half8 q1 = H8[(unsigned)(s1 * 8 + li)];
        half8 q2 = H8[(unsigned)(s2 * 8 + li)];
        half8 q3 = H8[(unsigned)(s3 * 8 + li)];
        float w0 = __builtin_amdgcn_exp2f(fmaxf(e0, NEG_SLOPE * e0));
        float w1 = __builtin_amdgcn_exp2f(fmaxf(e1, NEG_SLOPE * e1));
        float w2 = __builtin_amdgcn_exp2f(fmaxf(e2, NEG_SLOPE * e2));
        float w3 = __builtin_amdgcn_exp2f(fmaxf(e3, NEG_SLOPE * e3));
        half2v wp01; wp01[0] = (half_t)w0; wp01[1] = (half_t)w1;
        half2v wp23; wp23[0] = (half_t)w2; wp23[1] = (half_t)w3;
        #pragma unroll
        for (int f = 0; f < 8; ++f) {
            half2v p01; p01[0] = q0[f]; p01[1] = q1[f];
            half2v p23; p23[0] = q2[f]; p23[1] = q3[f];
            a[f] = FDOT2(p01, wp01, a[f]);
            a[f] = FDOT2(p23, wp23, a[f]);
        }
        den = FDOT2(wp01, one, den);
        den = FDOT2(wp23, one, den);
    }
    for (; j + 8 < end; j += 16) {         // 2-edge tail
        int s0 = esrc[j], s1 = esrc[j + 8];
        float e0 = As[s0] + adv;
        float e1 = As[s1] + adv;
        half8 q0 = H8[(unsigned)(s0 * 8 + li)];
        half8 q1 = H8[(unsigned)(s1 * 8 + li)];
        float w0 = __builtin_amdgcn_exp2f(fmaxf(e0, NEG_SLOPE * e0));
        float w1 = __builtin_amdgcn_exp2f(fmaxf(e1, NEG_SLOPE * e1));
        half2v wp; wp[0] = (half_t)w0; wp[1] = (half_t)w1;
        #pragma unroll
        for (int f = 0; f < 8; ++f) {
            half2v p; p[0] = q0[f]; p[1] = q1[f];
            a[f] = FDOT2(p, wp, a[f]);
        }
        den = FDOT2(wp, one, den);
    }
    for (; j < end; j += 8) {              // 1-edge tail
        int s = esrc[j];
        float e = As[s] + adv;
        half8 q0 = H8[(unsigned)(s * 8 + li)];
        float w = __builtin_amdgcn_exp2f(fmaxf(e, NEG_SLOPE * e));
        #pragma unroll
        for (int f = 0; f < 8; ++f) a[f] += w * (float)q0[f];
        den += w;
    }
    #pragma unroll
    for (int f = 0; f < 8; ++f) {
        a[f] += __shfl_xor(a[f], 8);
        a[f] += __shfl_xor(a[f], 16);
        a[f] += __shfl_xor(a[f], 32);
    }
    den += __shfl_xor(den, 8);
    den += __shfl_xor(den, 16);
    den += __shfl_xor(den, 32);
    if (lane < 8) {
        float inv = 1.f / (den + 1e-16f);
        float4 b0 = ((const float4*)bias)[2 * li];
        float4 b1 = ((const float4*)bias)[2 * li + 1];
        float4* o4 = (float4*)(out + (size_t)v * 64);
        o4[2 * li]     = make_float4(a[0] * inv + b0.x, a[1] * inv + b0.y,
                                     a[2] * inv + b0.z, a[3] * inv + b0.w);
        o4[2 * li + 1] = make_float4(a[4] * inv + b1.x, a[5] * inv + b1.y,
                                     a[6] * inv + b1.z, a[7] * inv + b1.w);
    }
}

extern "C" void kernel_launch(void* const* d_in, const int* in_sizes, int n_in,
                              void* d_out, int out_size, void* d_ws, size_t ws_size,
                              hipStream_t stream)
{
    (void)n_in; (void)out_size; (void)ws_size;
    const float* x   = (const float*)d_in[0];
    const int*   ei  = (const int*)  d_in[1];
    const float* W1  = (const float*)d_in[2];
    const float* as1 = (const float*)d_in[3];
    const float* ad1 = (const float*)d_in[4];
    const float* b1  = (const float*)d_in[5];
    const float* W2  = (const float*)d_in[6];
    const float* as2 = (const float*)d_in[7];
    const float* ad2 = (const float*)d_in[8];
    const float* b2  = (const float*)d_in[9];
    float* out = (float*)d_out;

    const int n    = in_sizes[0] / 128;   // 100000
    const int E    = in_sizes[1] / 2;     // 1600000
    const int Etot = E + n;               // + self loops
    const int NB   = (n + BKN - 1) / BKN; // buckets (782)
    const int chunk = (Etot + GRP - 1) / GRP;

    // Workspace layout (bytes).
    char* p = (char*)d_ws;
    half_t* Hh  = (half_t*)p; p += (size_t)n * 128 * sizeof(half_t);  // 25.6MB
    half_t* H2  = (half_t*)p; p += (size_t)n * 64 * sizeof(half_t);   // 12.8MB
    float* As1 = (float*)p;   p += (size_t)n * 4 * sizeof(float);
    float* Ad1 = (float*)p;   p += (size_t)n * 4 * sizeof(float);
    float* As2 = (float*)p;   p += (size_t)n * sizeof(float);
    float* Ad2 = (float*)p;   p += (size_t)n * sizeof(float);
    int* offs  = (int*)p;     p += (size_t)n * sizeof(int);
    int* esrc  = (int*)p;     p += (size_t)Etot * sizeof(int);
    unsigned* tmp = (unsigned*)p; p += (size_t)Etot * sizeof(unsigned);
    int* cnt   = (int*)p;     p += (size_t)NB * GRP * sizeof(int);    // 0.8MB
    int* bsum  = (int*)p;     p += 1024;
    half_t* Wt1 = (half_t*)p; p += 128 * 128 * sizeof(half_t);        // 32KB
    half_t* Wt2 = (half_t*)p; p += 64 * 128 * sizeof(half_t);         // 16KB

    const int scan_n  = NB * GRP;
    const int scan_nb = (scan_n + 1023) / 1024;   // 196 <= 256

    const int gtiles = (n + 63) / 64;

    // ---- CSR build (wconv folded into ghist; gemm1 fused into pass1) ----
    ghist_wconv<<<GRP, 256, 0, stream>>>(ei, E, Etot, NB, chunk, cnt, W1, Wt1, W2, Wt2);
    scan_blocks<<<scan_nb, 256, 0, stream>>>(cnt, scan_n, bsum);
    pass1_gemm1<<<GRP + gtiles, 256, 0, stream>>>(ei, E, Etot, NB, chunk, scan_nb, cnt, bsum, tmp,
                                                  x, Wt1, as1, ad1, Hh, As1, Ad1, n);
    pass2_sort<<<NB, 256, 0, stream>>>(tmp, cnt, bsum, NB, Etot, scan_nb, offs, esrc, n);

    // ---- Layer 1 aggregation + layer-2 GEMM (fused; gemm2 launch deleted) ----
    agg1_fused<<<(n * 64 + 255) / 256, 256, 0, stream>>>(
        offs, esrc, (const half8*)Hh, As1, Ad1, b1,
        Wt2, as2, ad2, H2, As2, Ad2, n);

    // ---- Layer 2 aggregation ----
    agg2<<<(n * 64 + 255) / 256, 256, 0, stream>>>(offs, esrc, (const half8*)H2, As2, Ad2, b2, out, n);
}

// Round 10
// 298.319 us; speedup vs baseline: 1.4966x; 1.0126x over previous
//
#include <hip/hip_runtime.h>
#include <hip/hip_fp16.h>

#define NEG_SLOPE 0.2f
#define BKN 128                 // nodes per bucket (pow2)
#define MAXNB 1024              // supports n <= 131072
#define GRP 256                 // pass1/ghist groups (blocks), private cursors
#define LOG2E 1.44269504f

typedef _Float16 half_t;
typedef __attribute__((ext_vector_type(2))) _Float16 half2v;
typedef __attribute__((ext_vector_type(4))) _Float16 half4;
typedef __attribute__((ext_vector_type(8))) _Float16 half8;
typedef __attribute__((ext_vector_type(4))) float floatx4;

#if __has_builtin(__builtin_amdgcn_fdot2)
#define FDOT2(a, b, c) __builtin_amdgcn_fdot2((a), (b), (c), false)
#else
#define FDOT2(a, b, c) ((float)(a)[0] * (float)(b)[0] + (float)(a)[1] * (float)(b)[1] + (c))
#endif

// ---------------------------------------------------------------------------
// MFMA GEMM + fused attention logits (mfma 16x16x32 f16, fp32 acc).
// Used standalone for layer 2; layer-1 instance lives inside pass1_gemm1.
// ---------------------------------------------------------------------------
template<int BN, int HEADS, bool INHALF>
__global__ __launch_bounds__(256) void gemm_mfma(
    const void* __restrict__ Xv, const half_t* __restrict__ Wt,
    const float* __restrict__ atts, const float* __restrict__ attd,
    half_t* __restrict__ H, float* __restrict__ As, float* __restrict__ Ad,
    int n)
{
    constexpr int K  = 128;
    constexpr int NT = BN / 16;           // col tiles
    constexpr int TPH = NT / HEADS;       // col tiles per head

    __shared__ half_t Wl[BN * K];
    __shared__ half_t Xl[64 * K];

    const int t = threadIdx.x;
    const int wave = t >> 6, lane = t & 63;
    const int quad = lane >> 4, c = lane & 15;

    float att_s[NT], att_d[NT];
    #pragma unroll
    for (int nt = 0; nt < NT; ++nt) {
        att_s[nt] = atts[nt * 16 + c] * LOG2E;
        att_d[nt] = attd[nt * 16 + c] * LOG2E;
    }

    for (int i = t; i < BN * 16; i += 256) {
        int row = i >> 4, cid = i & 15;
        half8 v = *(const half8*)(Wt + row * K + cid * 8);
        *(half8*)(Wl + row * K + ((cid ^ (row & 15)) << 3)) = v;
    }

    const int numTiles = (n + 63) / 64;
    for (int tile = blockIdx.x; tile < numTiles; tile += gridDim.x) {
        const int row0 = tile * 64;
        __syncthreads();
        for (int i = t; i < 1024; i += 256) {
            int m = i >> 4, cid = i & 15;
            int row = row0 + m;
            half8 h;
            #pragma unroll
            for (int z = 0; z < 8; ++z) h[z] = (half_t)0.f;
            if (row < n) {
                if constexpr (INHALF) {
                    h = *(const half8*)((const half_t*)Xv + (size_t)row * K + cid * 8);
                } else {
                    const float4* src = (const float4*)((const float*)Xv + (size_t)row * K + cid * 8);
                    float4 a = src[0], b = src[1];
                    h[0]=(half_t)a.x; h[1]=(half_t)a.y; h[2]=(half_t)a.z; h[3]=(half_t)a.w;
                    h[4]=(half_t)b.x; h[5]=(half_t)b.y; h[6]=(half_t)b.z; h[7]=(half_t)b.w;
                }
            }
            *(half8*)(Xl + m * K + ((cid ^ (m & 15)) << 3)) = h;
        }
        __syncthreads();

        floatx4 acc[NT];
        #pragma unroll
        for (int i = 0; i < NT; ++i) acc[i] = (floatx4)(0.f);

        #pragma unroll
        for (int kc = 0; kc < 4; ++kc) {
            int cid = kc * 4 + quad;
            half8 afrag = *(const half8*)(Xl + (wave * 16 + c) * K + ((cid ^ c) << 3));
            #pragma unroll
            for (int nt = 0; nt < NT; ++nt) {
                half8 bfrag = *(const half8*)(Wl + (nt * 16 + c) * K + ((cid ^ c) << 3));
                acc[nt] = __builtin_amdgcn_mfma_f32_16x16x32_f16(afrag, bfrag, acc[nt], 0, 0, 0);
            }
        }

        #pragma unroll
        for (int reg = 0; reg < 4; ++reg) {
            int row = row0 + wave * 16 + quad * 4 + reg;
            bool ok = row < n;
            if (ok) {
                #pragma unroll
                for (int nt = 0; nt < NT; ++nt)
                    H[(size_t)row * BN + nt * 16 + c] = (half_t)acc[nt][reg];
            }
            #pragma unroll
            for (int h = 0; h < HEADS; ++h) {
                float ps = 0.f, pd = 0.f;
                #pragma unroll
                for (int u = 0; u < TPH; ++u) {
                    int nt = h * TPH + u;
                    ps += acc[nt][reg] * att_s[nt];
                    pd += acc[nt][reg] * att_d[nt];
                }
                #pragma unroll
                for (int off = 1; off < 16; off <<= 1) {
                    ps += __shfl_xor(ps, off);
                    pd += __shfl_xor(pd, off);
                }
                if (ok && c == 0) {
                    As[(size_t)row * HEADS + h] = ps;
                    Ad[(size_t)row * HEADS + h] = pd;
                }
            }
        }
    }
}

// ---------------------------------------------------------------------------
// CSR build (2-level bucketed counting sort for scatter line-locality).
// NO per-node global atomics (round-6 evidence: they cost ~+35us).
// Weight convert for both layers folded in (first 96 blocks).
// ---------------------------------------------------------------------------
__global__ __launch_bounds__(256) void ghist_wconv(
    const int* __restrict__ ei, int E, int Etot, int NB, int chunk,
    int* __restrict__ cnt,
    const float* __restrict__ W1, half_t* __restrict__ Wt1,
    const float* __restrict__ W2, half_t* __restrict__ Wt2)
{
    int iw = blockIdx.x * 256 + threadIdx.x;
    if (iw < 128 * 128) {
        int k = iw / 128, nn = iw % 128;
        Wt1[nn * 128 + k] = (half_t)W1[iw];
    } else if (iw < 128 * 128 + 128 * 64) {
        int jx = iw - 128 * 128;
        int k = jx / 64, nn = jx % 64;
        Wt2[nn * 128 + k] = (half_t)W2[jx];
    }

    __shared__ int h[MAXNB];
    int g = blockIdx.x;
    for (int i = threadIdx.x; i < NB; i += 256) h[i] = 0;
    __syncthreads();
    int lo = g * chunk, hi = min(Etot, lo + chunk);
    for (int e = lo + threadIdx.x; e < hi; e += 256) {
        int dst = (e < E) ? ei[E + e] : (e - E);
        atomicAdd(&h[dst >> 7], 1);
    }
    __syncthreads();
    for (int i = threadIdx.x; i < NB; i += 256) cnt[i * GRP + g] = h[i];
}

// Per-1024 block scan (in-place exclusive); bsum = RAW block totals.
// Consumers prefix the <=256 totals themselves in LDS (scan_sums deleted).
__global__ __launch_bounds__(256) void scan_blocks(
    int* __restrict__ data, int n, int* __restrict__ bsum)
{
    __shared__ int s[256];
    int t = threadIdx.x;
    int idx = blockIdx.x * 1024 + t * 4;
    int4 v = make_int4(0, 0, 0, 0);
    if (idx + 3 < n)      v = *(const int4*)(data + idx);
    else {
        if (idx     < n) v.x = data[idx];
        if (idx + 1 < n) v.y = data[idx+1];
        if (idx + 2 < n) v.z = data[idx+2];
        if (idx + 3 < n) v.w = data[idx+3];
    }
    int tsum = v.x + v.y + v.z + v.w;
    s[t] = tsum;
    __syncthreads();
    for (int off = 1; off < 256; off <<= 1) {
        int x = (t >= off) ? s[t - off] : 0;
        __syncthreads();
        s[t] += x;
        __syncthreads();
    }
    int excl = s[t] - tsum;
    if (t == 255) bsum[blockIdx.x] = s[255];
    if (idx     < n) data[idx]     = excl;
    if (idx + 1 < n) data[idx + 1] = excl + v.x;
    if (idx + 2 < n) data[idx + 2] = excl + v.x + v.y;
    if (idx + 3 < n) data[idx + 3] = excl + v.x + v.y + v.z;
}

// ---------------------------------------------------------------------------
// FUSED: pass1_scatter (blocks [0,GRP)) + layer-1 MFMA GEMM (blocks >= GRP).
// pass1 branch prefixes the raw bsum totals in LDS (scratch overlays Wl so
// the kernel stays at 52KB -> 3 blocks/CU for the gemm path).
// ---------------------------------------------------------------------------
__global__ __launch_bounds__(256) void pass1_gemm1(
    const int* __restrict__ ei, int E, int Etot, int NB, int chunk, int nbC,
    const int* __restrict__ S, const int* __restrict__ bsum,
    unsigned* __restrict__ tmp,
    const float* __restrict__ X, const half_t* __restrict__ Wt,
    const float* __restrict__ atts, const float* __restrict__ attd,
    half_t* __restrict__ H, float* __restrict__ As, float* __restrict__ Ad,
    int n)
{
    constexpr int K = 128, BN = 128, NT = 8, HEADS = 4, TPH = 2;
    __shared__ half_t Wl[BN * K];          // 32KB (gemm path; pass1 scratch)
    __shared__ half_t Xl[64 * K];          // 16KB (gemm path)
    __shared__ int cur[MAXNB];             // 4KB  (pass1 path)

    const int t = threadIdx.x;

    if (blockIdx.x < GRP) {
        // ---------------- pass1_scatter ----------------
        int* bs  = (int*)Wl;               // [256] inclusive scan
        int* bse = (int*)Wl + 256;         // [256] exclusive prefix
        int g = blockIdx.x;
        int val = (t < nbC) ? bsum[t] : 0;
        bs[t] = val;
        __syncthreads();
        for (int off = 1; off < 256; off <<= 1) {
            int x = (t >= off) ? bs[t - off] : 0;
            __syncthreads();
            bs[t] += x;
            __syncthreads();
        }
        bse[t] = bs[t] - val;
        __syncthreads();
        for (int i = t; i < NB; i += 256) {
            int idx = i * GRP + g;
            cur[i] = S[idx] + bse[idx >> 10];
        }
        __syncthreads();
        int lo = g * chunk, hi = min(Etot, lo + chunk);
        for (int e = lo + t; e < hi; e += 256) {
            int src, dst;
            if (e < E) { src = ei[e]; dst = ei[E + e]; }
            else       { src = dst = e - E; }
            int pos = atomicAdd(&cur[dst >> 7], 1);   // LDS atomic, private row
            tmp[pos] = ((unsigned)src << 7) | (unsigned)(dst & (BKN - 1));
        }
        return;
    }

    // ---------------- layer-1 GEMM ----------------
    const int wave = t >> 6, lane = t & 63;
    const int quad = lane >> 4, c = lane & 15;

    float att_s[NT], att_d[NT];
    #pragma unroll
    for (int nt = 0; nt < NT; ++nt) {
        att_s[nt] = atts[nt * 16 + c] * LOG2E;
        att_d[nt] = attd[nt * 16 + c] * LOG2E;
    }

    for (int i = t; i < BN * 16; i += 256) {
        int row = i >> 4, cid = i & 15;
        half8 v = *(const half8*)(Wt + row * K + cid * 8);
        *(half8*)(Wl + row * K + ((cid ^ (row & 15)) << 3)) = v;
    }

    const int numTiles = (n + 63) / 64;
    for (int tile = blockIdx.x - GRP; tile < numTiles; tile += gridDim.x - GRP) {
        const int row0 = tile * 64;
        __syncthreads();
        for (int i = t; i < 1024; i += 256) {
            int m = i >> 4, cid = i & 15;
            int row = row0 + m;
            half8 h;
            #pragma unroll
            for (int z = 0; z < 8; ++z) h[z] = (half_t)0.f;
            if (row < n) {
                const float4* src = (const float4*)(X + (size_t)row * K + cid * 8);
                float4 a = src[0], b = src[1];
                h[0]=(half_t)a.x; h[1]=(half_t)a.y; h[2]=(half_t)a.z; h[3]=(half_t)a.w;
                h[4]=(half_t)b.x; h[5]=(half_t)b.y; h[6]=(half_t)b.z; h[7]=(half_t)b.w;
            }
            *(half8*)(Xl + m * K + ((cid ^ (m & 15)) << 3)) = h;
        }
        __syncthreads();

        floatx4 acc[NT];
        #pragma unroll
        for (int i = 0; i < NT; ++i) acc[i] = (floatx4)(0.f);

        #pragma unroll
        for (int kc = 0; kc < 4; ++kc) {
            int cid = kc * 4 + quad;
            half8 afrag = *(const half8*)(Xl + (wave * 16 + c) * K + ((cid ^ c) << 3));
            #pragma unroll
            for (int nt = 0; nt < NT; ++nt) {
                half8 bfrag = *(const half8*)(Wl + (nt * 16 + c) * K + ((cid ^ c) << 3));
                acc[nt] = __builtin_amdgcn_mfma_f32_16x16x32_f16(afrag, bfrag, acc[nt], 0, 0, 0);
            }
        }

        #pragma unroll
        for (int reg = 0; reg < 4; ++reg) {
            int row = row0 + wave * 16 + quad * 4 + reg;
            bool ok = row < n;
            if (ok) {
                #pragma unroll
                for (int nt = 0; nt < NT; ++nt)
                    H[(size_t)row * BN + nt * 16 + c] = (half_t)acc[nt][reg];
            }
            #pragma unroll
            for (int h = 0; h < HEADS; ++h) {
                float ps = 0.f, pd = 0.f;
                #pragma unroll
                for (int u = 0; u < TPH; ++u) {
                    int nt = h * TPH + u;
                    ps += acc[nt][reg] * att_s[nt];
                    pd += acc[nt][reg] * att_d[nt];
                }
                #pragma unroll
                for (int off = 1; off < 16; off <<= 1) {
                    ps += __shfl_xor(ps, off);
                    pd += __shfl_xor(pd, off);
                }
                if (ok && c == 0) {
                    As[(size_t)row * HEADS + h] = ps;
                    Ad[(size_t)row * HEADS + h] = pd;
                }
            }
        }
    }
}

// ---------------------------------------------------------------------------
// pass2_sort: count + scan + scatter (two streams over tmp; round-5 proven).
// Block-sum prefix folded in-LDS (scan_sums launch deleted).
// ---------------------------------------------------------------------------
__global__ __launch_bounds__(256) void pass2_sort(
    const unsigned* __restrict__ tmp, const int* __restrict__ S,
    const int* __restrict__ bsum, int NB, int Etot, int nbC,
    int* __restrict__ offs, int* __restrict__ esrc, int n)
{
    __shared__ int cnt[BKN];
    __shared__ int sc[BKN];
    __shared__ int cur[BKN];
    __shared__ int bs[256];
    __shared__ int bse[256];
    int bk = blockIdx.x;
    int t  = threadIdx.x;

    int val = (t < nbC) ? bsum[t] : 0;
    bs[t] = val;
    if (t < BKN) cnt[t] = 0;
    __syncthreads();
    for (int off = 1; off < 256; off <<= 1) {
        int x = (t >= off) ? bs[t - off] : 0;
        __syncthreads();
        bs[t] += x;
        __syncthreads();
    }
    bse[t] = bs[t] - val;
    __syncthreads();

    int lo = S[bk * GRP] + bse[(bk * GRP) >> 10];
    int hi = (bk + 1 < NB) ? (S[(bk + 1) * GRP] + bse[((bk + 1) * GRP) >> 10]) : Etot;

    for (int i = lo + t; i < hi; i += 256)
        atomicAdd(&cnt[tmp[i] & (BKN - 1)], 1);
    __syncthreads();
    int v = (t < BKN) ? cnt[t] : 0;
    if (t < BKN) sc[t] = v;
    __syncthreads();
    for (int off = 1; off < BKN; off <<= 1) {
        int x = (t < BKN && t >= off) ? sc[t - off] : 0;
        __syncthreads();
        if (t < BKN) sc[t] += x;
        __syncthreads();
    }
    if (t < BKN) {
        int node = bk * BKN + t;
        if (node < n) offs[node] = lo + sc[t];   // inclusive scan -> end(v)
        cur[t] = lo + sc[t] - v;                 // exclusive -> begin cursor
    }
    __syncthreads();
    for (int i = lo + t; i < hi; i += 256) {
        unsigned w = tmp[i];
        int p = atomicAdd(&cur[w & (BKN - 1)], 1);
        esrc[p] = (int)(w >> 7);
    }
}

// ---------------------------------------------------------------------------
// Layer-1 aggregation: one wave per dst node; QUARTER-WAVE per edge.
// 4-edge unroll per slot (16 edges/iter/wave); dot2 MAC; exp2 logits.
// Fuses normalize + bias + ELU; writes X2 in fp16.
// ---------------------------------------------------------------------------
__global__ __launch_bounds__(256) void agg1(
    const int* __restrict__ offs, const int* __restrict__ esrc,
    const half8* __restrict__ H8, const float* __restrict__ As,
    const float* __restrict__ Ad, const float* __restrict__ bias,
    half_t* __restrict__ X2h, int n)
{
    int v    = (blockIdx.x * 256 + threadIdx.x) >> 6;
    int lane = threadIdx.x & 63;
    if (v >= n) return;
    int q    = lane >> 4;        // quarter 0..3, one edge each
    int li   = lane & 15;        // feature lane: feats 8li..8li+7
    int head = li >> 2;          // 32 feats/head, 8 feats/lane -> 4 lanes/head
    int end = offs[v];
    int beg = v ? offs[v - 1] : 0;
    float adv = Ad[(size_t)v * 4 + head];
    half2v one; one[0] = (half_t)1.f; one[1] = (half_t)1.f;
    float a[8];
    #pragma unroll
    for (int f = 0; f < 8; ++f) a[f] = 0.f;
    float den = 0.f;
    int j = beg + q;
    for (; j + 12 < end; j += 16) {        // 4 edges per slot per iter
        int s0 = esrc[j], s1 = esrc[j + 4], s2 = esrc[j + 8], s3 = esrc[j + 12];
        float e0 = As[(unsigned)(s0 * 4 + head)] + adv;
        float e1 = As[(unsigned)(s1 * 4 + head)] + adv;
        float e2 = As[(unsigned)(s2 * 4 + head)] + adv;
        float e3 = As[(unsigned)(s3 * 4 + head)] + adv;
        half8 q0 = H8[(unsigned)(s0 * 16 + li)];
        half8 q1 = H8[(unsigned)(s1 * 16 + li)];
        half8 q2 = H8[(unsigned)(s2 * 16 + li)];
        half8 q3 = H8[(unsigned)(s3 * 16 + li)];
        float w0 = __builtin_amdgcn_exp2f(fmaxf(e0, NEG_SLOPE * e0));
        float w1 = __builtin_amdgcn_exp2f(fmaxf(e1, NEG_SLOPE * e1));
        float w2 = __builtin_amdgcn_exp2f(fmaxf(e2, NEG_SLOPE * e2));
        float w3 = __builtin_amdgcn_exp2f(fmaxf(e3, NEG_SLOPE * e3));
        half2v wp01; wp01[0] = (half_t)w0; wp01[1] = (half_t)w1;
        half2v wp23; wp23[0] = (half_t)w2; wp23[1] = (half_t)w3;
        #pragma unroll
        for (int f = 0; f < 8; ++f) {
            half2v p01; p01[0] = q0[f]; p01[1] = q1[f];
            half2v p23; p23[0] = q2[f]; p23[1] = q3[f];
            a[f] = FDOT2(p01, wp01, a[f]);
            a[f] = FDOT2(p23, wp23, a[f]);
        }
        den = FDOT2(wp01, one, den);
        den = FDOT2(wp23, one, den);
    }
    for (; j + 4 < end; j += 8) {          // 2-edge tail
        int s0 = esrc[j], s1 = esrc[j + 4];
        float e0 = As[(unsigned)(s0 * 4 + head)] + adv;
        float e1 = As[(unsigned)(s1 * 4 + head)] + adv;
        half8 q0 = H8[(unsigned)(s0 * 16 + li)];
        half8 q1 = H8[(unsigned)(s1 * 16 + li)];
        float w0 = __builtin_amdgcn_exp2f(fmaxf(e0, NEG_SLOPE * e0));
        float w1 = __builtin_amdgcn_exp2f(fmaxf(e1, NEG_SLOPE * e1));
        half2v wp; wp[0] = (half_t)w0; wp[1] = (half_t)w1;
        #pragma unroll
        for (int f = 0; f < 8; ++f) {
            half2v p; p[0] = q0[f]; p[1] = q1[f];
            a[f] = FDOT2(p, wp, a[f]);
        }
        den = FDOT2(wp, one, den);
    }
    for (; j < end; j += 4) {              // 1-edge tail
        int s = esrc[j];
        float e = As[(unsigned)(s * 4 + head)] + adv;
        half8 q0 = H8[(unsigned)(s * 16 + li)];
        float w = __builtin_amdgcn_exp2f(fmaxf(e, NEG_SLOPE * e));
        #pragma unroll
        for (int f = 0; f < 8; ++f) a[f] += w * (float)q0[f];
        den += w;
    }
    #pragma unroll
    for (int f = 0; f < 8; ++f) {
        a[f] += __shfl_xor(a[f], 16);
        a[f] += __shfl_xor(a[f], 32);
    }
    den += __shfl_xor(den, 16);
    den += __shfl_xor(den, 32);
    if (q == 0) {
        float inv = 1.f / (den + 1e-16f);
        float4 b0 = ((const float4*)bias)[2 * li];
        float4 b1 = ((const float4*)bias)[2 * li + 1];
        float o[8];
        o[0] = a[0] * inv + b0.x; o[1] = a[1] * inv + b0.y;
        o[2] = a[2] * inv + b0.z; o[3] = a[3] * inv + b0.w;
        o[4] = a[4] * inv + b1.x; o[5] = a[5] * inv + b1.y;
        o[6] = a[6] * inv + b1.z; o[7] = a[7] * inv + b1.w;
        half8 h;
        #pragma unroll
        for (int f = 0; f < 8; ++f) {
            float e = o[f] > 0.f ? o[f] : __expf(o[f]) - 1.f;
            h[f] = (half_t)e;
        }
        *(half8*)(X2h + (size_t)v * 128 + li * 8) = h;
    }
}

// ---------------------------------------------------------------------------
// Layer-2 aggregation: one wave per dst node; EIGHTH-WAVE per edge.
// 4-edge unroll per slot (32 edges/iter/wave); dot2 MAC; exp2 logits.
// ---------------------------------------------------------------------------
__global__ __launch_bounds__(256) void agg2(
    const int* __restrict__ offs, const int* __restrict__ esrc,
    const half8* __restrict__ H8, const float* __restrict__ As,
    const float* __restrict__ Ad, const float* __restrict__ bias,
    float* __restrict__ out, int n)
{
    int v    = (blockIdx.x * 256 + threadIdx.x) >> 6;
    int lane = threadIdx.x & 63;
    if (v >= n) return;
    int g  = lane >> 3;          // group 0..7, one edge each
    int li = lane & 7;           // feats 8li..8li+7
    int end = offs[v];
    int beg = v ? offs[v - 1] : 0;
    float adv = Ad[v];
    half2v one; one[0] = (half_t)1.f; one[1] = (half_t)1.f;
    float a[8];
    #pragma unroll
    for (int f = 0; f < 8; ++f) a[f] = 0.f;
    float den = 0.f;
    int j = beg + g;
    for (; j + 24 < end; j += 32) {        // 4 edges per slot per iter
        int s0 = esrc[j], s1 = esrc[j + 8], s2 = esrc[j + 16], s3 = esrc[j + 24];
        float e0 = As[s0] + adv;
        float e1 = As[s1] + adv;
        float e2 = As[s2] + adv;
        float e3 = As[s3] + adv;
        half8 q0 = H8[(unsigned)(s0 * 8 + li)];
        half8 q1 = H8[(unsigned)(s1 * 8 + li)];
        half8 q2 = H8[(unsigned)(s2 * 8 + li)];
        half8 q3 = H8[(unsigned)(s3 * 8 + li)];
        float w0 = __builtin_amdgcn_exp2f(fmaxf(e0, NEG_SLOPE * e0));
        float w1 = __builtin_amdgcn_exp2f(fmaxf(e1, NEG_SLOPE * e1));
        float w2 = __builtin_amdgcn_exp2f(fmaxf(e2, NEG_SLOPE * e2));
        float w3 = __builtin_amdgcn_exp2f(fmaxf(e3, NEG_SLOPE * e3));
        half2v wp01; wp01[0] = (half_t)w0; wp01[1] = (half_t)w1;
        half2v wp23; wp23[0] = (half_t)w2; wp23[1] = (half_t)w3;
        #pragma unroll
        for (int f = 0; f < 8; ++f) {
            half2v p01; p01[0] = q0[f]; p01[1] = q1[f];
            half2v p23; p23[0] = q2[f]; p23[1] = q3[f];
            a[f] = FDOT2(p01, wp01, a[f]);
            a[f] = FDOT2(p23, wp23, a[f]);
        }
        den = FDOT2(wp01, one, den);
        den = FDOT2(wp23, one, den);
    }
    for (; j + 8 < end; j += 16) {         // 2-edge tail
        int s0 = esrc[j], s1 = esrc[j + 8];
        float e0 = As[s0] + adv;
        float e1 = As[s1] + adv;
        half8 q0 = H8[(unsigned)(s0 * 8 + li)];
        half8 q1 = H8[(unsigned)(s1 * 8 + li)];
        float w0 = __builtin_amdgcn_exp2f(fmaxf(e0, NEG_SLOPE * e0));
        float w1 = __builtin_amdgcn_exp2f(fmaxf(e1, NEG_SLOPE * e1));
        half2v wp; wp[0] = (half_t)w0; wp[1] = (half_t)w1;
        #pragma unroll
        for (int f = 0; f < 8; ++f) {
            half2v p; p[0] = q0[f]; p[1] = q1[f];
            a[f] = FDOT2(p, wp, a[f]);
        }
        den = FDOT2(wp, one, den);
    }
    for (; j < end; j += 8) {              // 1-edge tail
        int s = esrc[j];
        float e = As[s] + adv;
        half8 q0 = H8[(unsigned)(s * 8 + li)];
        float w = __builtin_amdgcn_exp2f(fmaxf(e, NEG_SLOPE * e));
        #pragma unroll
        for (int f = 0; f < 8; ++f) a[f] += w * (float)q0[f];
        den += w;
    }
    #pragma unroll
    for (int f = 0; f < 8; ++f) {
        a[f] += __shfl_xor(a[f], 8);
        a[f] += __shfl_xor(a[f], 16);
        a[f] += __shfl_xor(a[f], 32);
    }
    den += __shfl_xor(den, 8);
    den += __shfl_xor(den, 16);
    den += __shfl_xor(den, 32);
    if (lane < 8) {
        float inv = 1.f / (den + 1e-16f);
        float4 b0 = ((const float4*)bias)[2 * li];
        float4 b1 = ((const float4*)bias)[2 * li + 1];
        float4* o4 = (float4*)(out + (size_t)v * 64);
        o4[2 * li]     = make_float4(a[0] * inv + b0.x, a[1] * inv + b0.y,
                                     a[2] * inv + b0.z, a[3] * inv + b0.w);
        o4[2 * li + 1] = make_float4(a[4] * inv + b1.x, a[5] * inv + b1.y,
                                     a[6] * inv + b1.z, a[7] * inv + b1.w);
    }
}

extern "C" void kernel_launch(void* const* d_in, const int* in_sizes, int n_in,
                              void* d_out, int out_size, void* d_ws, size_t ws_size,
                              hipStream_t stream)
{
    (void)n_in; (void)out_size; (void)ws_size;
    const float* x   = (const float*)d_in[0];
    const int*   ei  = (const int*)  d_in[1];
    const float* W1  = (const float*)d_in[2];
    const float* as1 = (const float*)d_in[3];
    const float* ad1 = (const float*)d_in[4];
    const float* b1  = (const float*)d_in[5];
    const float* W2  = (const float*)d_in[6];
    const float* as2 = (const float*)d_in[7];
    const float* ad2 = (const float*)d_in[8];
    const float* b2  = (const float*)d_in[9];
    float* out = (float*)d_out;

    const int n    = in_sizes[0] / 128;   // 100000
    const int E    = in_sizes[1] / 2;     // 1600000
    const int Etot = E + n;               // + self loops
    const int NB   = (n + BKN - 1) / BKN; // buckets (782)
    const int chunk = (Etot + GRP - 1) / GRP;

    // Workspace layout (bytes). Layer-2 buffers overlay consumed layer-1 ones.
    char* p = (char*)d_ws;
    half_t* Hh  = (half_t*)p; p += (size_t)n * 128 * sizeof(half_t);  // 25.6MB
    half_t* X2h = (half_t*)p; p += (size_t)n * 128 * sizeof(half_t);  // 25.6MB
    float* As1 = (float*)p;   p += (size_t)n * 4 * sizeof(float);     // (L2: As2=n)
    float* Ad1 = (float*)p;   p += (size_t)n * 4 * sizeof(float);     // (L2: Ad2=n)
    int* offs  = (int*)p;     p += (size_t)n * sizeof(int);
    int* esrc  = (int*)p;     p += (size_t)Etot * sizeof(int);
    unsigned* tmp = (unsigned*)p; p += (size_t)Etot * sizeof(unsigned);
    int* cnt   = (int*)p;     p += (size_t)NB * GRP * sizeof(int);    // 0.8MB
    int* bsum  = (int*)p;     p += 1024;
    half_t* Wt1 = (half_t*)p; p += 128 * 128 * sizeof(half_t);        // 32KB
    half_t* Wt2 = (half_t*)p; p += 64 * 128 * sizeof(half_t);         // 16KB

    const int scan_n  = NB * GRP;
    const int scan_nb = (scan_n + 1023) / 1024;   // 196 <= 256

    const int gtiles = (n + 63) / 64;

    // ---- CSR build (wconv folded into ghist; gemm1 fused into pass1;
    //      scan_sums deleted -- consumers prefix bsum in LDS) ----
    ghist_wconv<<<GRP, 256, 0, stream>>>(ei, E, Etot, NB, chunk, cnt, W1, Wt1, W2, Wt2);
    scan_blocks<<<scan_nb, 256, 0, stream>>>(cnt, scan_n, bsum);
    pass1_gemm1<<<GRP + gtiles, 256, 0, stream>>>(ei, E, Etot, NB, chunk, scan_nb, cnt, bsum, tmp,
                                                  x, Wt1, as1, ad1, Hh, As1, Ad1, n);
    pass2_sort<<<NB, 256, 0, stream>>>(tmp, cnt, bsum, NB, Etot, scan_nb, offs, esrc, n);

    // ---- Layer 1 aggregation ----
    agg1<<<(n * 64 + 255) / 256, 256, 0, stream>>>(offs, esrc, (const half8*)Hh, As1, Ad1, b1, X2h, n);

    // ---- Layer 2 ----
    gemm_mfma<64, 1, true><<<gtiles, 256, 0, stream>>>(X2h, Wt2, as2, ad2, Hh, As1, Ad1, n);
    agg2<<<(n * 64 + 255) / 256, 256, 0, stream>>>(offs, esrc, (const half8*)Hh, As1, Ad1, b2, out, n);
}